// Round 16
// baseline (43.512 us; speedup 1.0000x reference)
//
#include <hip/hip_runtime.h>
#include <math.h>

#define B 64
#define NI 1024
#define NO 1024
#define NC 10
#define NPH 8       // k-phases per block
#define KPH 128     // k per phase (8 granules of 8k per row... 16 granules)

typedef float f4 __attribute__((ext_vector_type(4)));
typedef float f2 __attribute__((ext_vector_type(2)));
typedef _Float16 h8 __attribute__((ext_vector_type(8)));
typedef _Float16 h2 __attribute__((ext_vector_type(2)));

// log(tanh(100*ax)) for ax>=0 via hw exp/log: tanh(z) = 1 - 2/(e^{2z}+1).
// ax==0 -> -inf -> clamp -60000 (f16-representable; f32 sums of sentinels stay
// very negative -> exp underflows to 0 == masked product containing a zero).
// Large ax: e=inf -> th=1 -> log = 0 exactly.
__device__ __forceinline__ float lt_fast(float ax) {
    float e  = __expf(200.0f * ax);
    float th = 1.0f - 2.0f / (e + 1.0f);
    return fmaxf(__logf(th), -60000.0f);
}

// One full layer in one kernel. Grid 64 = NO/16; block 1024 thr = 16 waves.
// Block computes 16 o x 64 b over k=1024 in 8 double-buffered 128-k phases.
// Wave w = (bq = w&3, ks2 = w>>2): b-quadrant bq, k-stripe ks2 (32k per phase).
// End: in-block f32 reduce over ks2, finalize h = relu(sh*exp(ss)) inline.
// FIRST: input raw f32 x [B][NI], outputs xp[b][NI] (h,lt) pairs + xh[o][B].
// else : input xp pairs, outputs xh[o][B] only.
template<bool FIRST>
__global__ __launch_bounds__(1024) void layer_k(
    const float* __restrict__ xraw, const h2* __restrict__ xp_in,
    const float* __restrict__ fc, const float* __restrict__ v,
    h2* __restrict__ xp_out, _Float16* __restrict__ xh,
    float* __restrict__ y)
{
    const int blk = blockIdx.x, t = threadIdx.x;
    const int o0 = blk * 16;

    if (FIRST && blk == 0 && t < (B * NC) / 4) {   // zero y for head atomics
        f4 z; z.x = 0.f; z.y = 0.f; z.z = 0.f; z.w = 0.f;
        ((f4*)y)[t] = z;
    }

    __shared__ h8 sWf[2][16][16];   // 8 KB   fc*m   [buf][o][granule]
    __shared__ h8 sWm[2][16][16];   // 8 KB   m
    __shared__ h8 sX [2][B][16];    // 32 KB  x      [buf][b][granule]
    __shared__ h8 sL [2][B][16];    // 32 KB  lt
    __shared__ float redH[4][4][16][16];   // 16 KB [ks2][bq][o][b16]
    __shared__ float redS[4][4][16][16];   // 16 KB

    const int w = t >> 6, l = t & 63;
    const int r16 = l & 15, ks = l >> 4;
    const int bq = w & 3, ks2 = w >> 2;
    f4 accH = {}, accS = {};

    // ---- stage phase p into buffer bf (R8-proven conversion text) ----
    auto STAGE = [&](int p, int bf) {
        if (t < 256) {   // weights: thread = (o = t>>4, g = t&15), 8 k each
            const int o = t >> 4, g = t & 15;
            const float* fp = &fc[(size_t)(o0 + o) * NI + p * KPH + g * 8];
            const float* vp = &v [(size_t)(o0 + o) * NI + p * KPH + g * 8];
            f4 fa = *(const f4*)fp, fb = *(const f4*)(fp + 4);
            f4 va = *(const f4*)vp, vb = *(const f4*)(vp + 4);
            h8 wf, wm;
            #pragma unroll
            for (int j = 0; j < 4; ++j) {
                bool ma = va[j] > 0.0f, mb = vb[j] > 0.0f;
                wf[j]     = ma ? (_Float16)fa[j] : (_Float16)0.0f;
                wm[j]     = ma ? (_Float16)1.0f  : (_Float16)0.0f;
                wf[4 + j] = mb ? (_Float16)fb[j] : (_Float16)0.0f;
                wm[4 + j] = mb ? (_Float16)1.0f  : (_Float16)0.0f;
            }
            sWf[bf][o][g ^ (o & 7)] = wf;
            sWm[bf][o][g ^ (o & 7)] = wm;
        }
        // activations: thread = (b = t>>4, g = t&15), 8 k each — full coverage
        {
            const int b = t >> 4, g = t & 15;
            h8 xv, lv;
            if (FIRST) {
                const float* xr = &xraw[(size_t)b * NI + p * KPH + g * 8];
                f4 xa = *(const f4*)xr, xb = *(const f4*)(xr + 4);
                #pragma unroll
                for (int j = 0; j < 4; ++j) {
                    xv[j]     = (_Float16)xa[j];
                    lv[j]     = (_Float16)lt_fast(fabsf(xa[j]));
                    xv[4 + j] = (_Float16)xb[j];
                    lv[4 + j] = (_Float16)lt_fast(fabsf(xb[j]));
                }
            } else {
                const f4* s4 = (const f4*)&xp_in[(size_t)b * NI + p * KPH + g * 8];
                f4 q0 = s4[0], q1 = s4[1];
                #pragma unroll
                for (int jj = 0; jj < 4; ++jj) {
                    h2 p0 = __builtin_bit_cast(h2, q0[jj]);
                    h2 p1 = __builtin_bit_cast(h2, q1[jj]);
                    xv[jj] = p0.x;     lv[jj] = p0.y;
                    xv[4 + jj] = p1.x; lv[4 + jj] = p1.y;
                }
            }
            sX[bf][b][g ^ (b & 7)] = xv;
            sL[bf][b][g ^ (b & 7)] = lv;
        }
    };

    // ---- compute phase p from buffer bf: one MFMA per reduction per wave ----
    auto COMPUTE = [&](int bf) {
        const int g = (ks2 * 4 + ks) ^ (r16 & 7);   // wave's 32-k stripe granule
        h8 aF = sWf[bf][r16][g];
        h8 aM = sWm[bf][r16][g];
        h8 bX = sX[bf][bq * 16 + r16][g];
        h8 bL = sL[bf][bq * 16 + r16][g];
        accH = __builtin_amdgcn_mfma_f32_16x16x32_f16(aF, bX, accH, 0, 0, 0);
        accS = __builtin_amdgcn_mfma_f32_16x16x32_f16(aM, bL, accS, 0, 0, 0);
    };

    STAGE(0, 0);
    __syncthreads();
    #pragma unroll
    for (int p = 0; p < NPH; ++p) {
        if (p + 1 < NPH) STAGE(p + 1, (p + 1) & 1);
        COMPUTE(p & 1);
        __syncthreads();
    }

    // ---- in-block reduce over ks2: write partials (m89 D layout) ----
    #pragma unroll
    for (int r = 0; r < 4; ++r) {
        redH[ks2][bq][ks * 4 + r][r16] = accH[r];   // row = o_loc, col = b16
        redS[ks2][bq][ks * 4 + r][r16] = accS[r];
    }
    __syncthreads();

    // ---- finalize: thread = (o = t>>6, b = t&63) ----
    {
        const int o = t >> 6, b = t & 63;
        const int bq2 = b >> 4, b16 = b & 15;
        float sh = (redH[0][bq2][o][b16] + redH[1][bq2][o][b16])
                 + (redH[2][bq2][o][b16] + redH[3][bq2][o][b16]);
        float ss = (redS[0][bq2][o][b16] + redS[1][bq2][o][b16])
                 + (redS[2][bq2][o][b16] + redS[3][bq2][o][b16]);
        float h = fmaxf(sh * __expf(ss), 0.0f);
        const int og = o0 + o;
        xh[(size_t)og * B + b] = (_Float16)h;      // o-major [o][B], coalesced
        if (FIRST) {
            h2 pr; pr.x = (_Float16)h; pr.y = (_Float16)lt_fast(h);
            xp_out[(size_t)b * NI + og] = pr;      // scattered 4B, L2-absorbed
        }
    }
}

// ---------------- Head (grid 16): L2-hot xh only + 16-contender atomics -----
__global__ __launch_bounds__(256) void head_k(
    const _Float16* __restrict__ xh0, const _Float16* __restrict__ xh1,
    const float* __restrict__ hd0, const float* __restrict__ hd1,
    float* __restrict__ y)
{
    const int blk = blockIdx.x, t = threadIdx.x;
    const int o0 = blk * 64;
    __shared__ float hh0[64][65];   // stride 65 (odd): column access bank-free
    __shared__ float hh1[64][65];
    __shared__ f2 hdl[NC][64];

    #pragma unroll
    for (int rep = 0; rep < 16; ++rep) {
        const int cell = t + rep * 256;
        const int ol = cell >> 6, b = cell & 63;   // both xh o-major [o][B]
        hh0[ol][b] = (float)xh0[(size_t)(o0 + ol) * B + b];
        hh1[ol][b] = (float)xh1[(size_t)(o0 + ol) * B + b];
    }
    for (int e = t; e < NC * 64; e += 256) {
        const int c = e >> 6, ol = e & 63;
        f2 d; d.x = hd0[c * NO + o0 + ol]; d.y = hd1[c * NO + o0 + ol];
        hdl[c][ol] = d;
    }
    __syncthreads();

    const int w = t >> 6, lane = t & 63;
    for (int cc = w; cc < NC; cc += 4) {
        float acc = 0.f;
        #pragma unroll 8
        for (int ol = 0; ol < 64; ++ol) {
            f2 dv = hdl[cc][ol];                    // wave-uniform broadcast
            acc = fmaf(hh0[ol][lane], dv.x, fmaf(hh1[ol][lane], dv.y, acc));
        }
        atomicAdd(&y[lane * NC + cc], acc);         // 16 contenders (R6/R8-proven)
    }
}

extern "C" void kernel_launch(void* const* d_in, const int* in_sizes, int n_in,
                              void* d_out, int out_size, void* d_ws, size_t ws_size,
                              hipStream_t stream) {
    const float* x   = (const float*)d_in[0];
    const float* v0  = (const float*)d_in[1];
    const float* fc0 = (const float*)d_in[2];
    const float* hd0 = (const float*)d_in[3];
    const float* v1  = (const float*)d_in[4];
    const float* fc1 = (const float*)d_in[5];
    const float* hd1 = (const float*)d_in[6];
    float* y = (float*)d_out;

    h2* xp        = (h2*)d_ws;                          // 256 KB [b][NI] (h,lt)
    _Float16* xh0 = (_Float16*)(xp + (size_t)B * NI);   // 128 KB [o][B]
    _Float16* xh1 = xh0 + (size_t)NO * B;               // 128 KB [o][B]

    layer_k<true ><<<NO / 16, 1024, 0, stream>>>(x, nullptr, fc0, v0, xp, xh0, y);
    layer_k<false><<<NO / 16, 1024, 0, stream>>>(nullptr, xp, fc1, v1, nullptr, xh1, nullptr);
    head_k        <<<16, 256, 0, stream>>>(xh0, xh1, hd0, hd1, y);
}